// Round 3
// baseline (10161.853 us; speedup 1.0000x reference)
//
#include <hip/hip_runtime.h>
#include <hip/hip_bf16.h>

// LSTM B=128,T=2048,H=256. R3: 32 WGs x 512 threads (8 waves, 256 VGPR/wave).
//  prep: (a) WXA combo table bf16(Wih[:,x]+Wih[:,64+a]+bih+bhh) for 1024 (x,a)
//        combos, [c][j][p] layout, 2 MB; (b) packed per-(t,b) records
//        {c=x*16+a | done<<16, rw fp32} 8B, [wg][t][4]; (c) obf bf16
//        B-fragments for Whh classes g,o (256 KB).
//  rec:  wave w owns 32 gate columns (2 MFMA col-blocks). Weights: classes i,f
//        (all kst) + g kst0-1 in ARCH VGPRs (144 regs; 512-thr WG => 256/wave
//        budget, no accvgpr-move tax); class o fully in LDS (128 KB); g kst2-7
//        streamed from L2-resident obf (step-invariant). A-rows 4..15 are zero
//        padding: af ds_reads exec-masked to lanes lm<4 (4x less LDS traffic).
//        MFMA results redistributed via 16 KB gbuf -> dense epilogue, 2 h-vals
//        per thread. bar2 is lgkm-only so out[] stores drain off the serial path.

namespace {

constexpr int Tt   = 2048;
constexpr int Bb   = 128;
constexpr int Hh   = 256;
constexpr int NBat = 16;   // fallback kernel rows/WG
constexpr int NBR  = 4;    // lstm_rec rows/WG (32 WGs)
constexpr int LDP  = 264;  // fallback hbuf pitch
constexpr int LDP2 = 272;  // rec hbuf pitch (bank-safe for masked af reads)
constexpr int INED = 82;

constexpr size_t REC_OFF   = 0;
constexpr size_t REC_BYTES = (size_t)Bb * Tt * 8;        // 2 MB
constexpr size_t WXA_OFF   = REC_OFF + REC_BYTES;
constexpr size_t WXA_BYTES = (size_t)1024 * 1024 * 2;    // 2 MB
constexpr size_t OBF_OFF   = WXA_OFF + WXA_BYTES;
constexpr size_t OBF_BYTES = (size_t)2 * 16 * 8 * 64 * 16;  // 256 KB
constexpr size_t WS_NEED   = OBF_OFF + OBF_BYTES;

typedef __attribute__((ext_vector_type(8))) short short8;
typedef __attribute__((ext_vector_type(4))) float float4v;
typedef __attribute__((ext_vector_type(4))) unsigned short us4;

__device__ inline unsigned short bf16u(float f) {
  unsigned u = __float_as_uint(f);
  unsigned r = (u + 0x7FFFu + ((u >> 16) & 1u)) >> 16;  // RNE
  return (unsigned short)r;
}
__device__ inline float u2f(unsigned short u) {
  return __uint_as_float(((unsigned)u) << 16);
}
__device__ inline float sigf(float x) {
  float e = __builtin_amdgcn_exp2f(-1.4426950408889634f * x);
  return __builtin_amdgcn_rcpf(1.0f + e);
}
__device__ inline float tanhf_fast(float x) {
  float ax = __builtin_fabsf(x);
  float e  = __builtin_amdgcn_exp2f(-2.8853900817779268f * ax);
  float r  = (1.0f - e) * __builtin_amdgcn_rcpf(1.0f + e);
  return __builtin_copysignf(r, x);
}

// ---------------- prep: WXA table (+bias), packed records, Whh g/o fragments ----------------
__global__ __launch_bounds__(256) void prep_kernel(
    const int* __restrict__ xs, const int* __restrict__ pa,
    const float* __restrict__ prw, const float* __restrict__ pdn,
    const float* __restrict__ Wih, const float* __restrict__ Whh,
    const float* __restrict__ bih, const float* __restrict__ bhh,
    unsigned char* __restrict__ ws)
{
  const int T1 = 1024 * 1024;      // WXA elements
  const int T2 = Bb * Tt;          // records
  const int T3 = 2 * 16 * 8 * 64;  // obf fragments
  int id = blockIdx.x * 256 + threadIdx.x;
  if (id < T1) {
    // WXA[c][j][p] = bf16(Wih[g][x] + Wih[g][64+a] + bih[g] + bhh[g]), g=p*256+j
    int c = id >> 10, q = id & 1023, jj = q >> 2, p = q & 3;
    int x = c >> 4, a = c & 15;
    int g = p * 256 + jj;
    const float* row = Wih + (size_t)g * INED;
    ((unsigned short*)(ws + WXA_OFF))[id] = bf16u(row[x] + row[64 + a] + bih[g] + bhh[g]);
  } else if (id < T1 + T2) {
    int id2 = id - T1;
    int t = id2 & (Tt - 1), bg = id2 >> 11;
    const size_t src = (size_t)bg * Tt + t;
    int xv = xs[src], av = pa[src];
    float rw = prw[src];
    unsigned dnb = (pdn[src] != 0.0f) ? 1u : 0u;
    uint2 r;
    r.x = (unsigned)(xv * 16 + av) | (dnb << 16);
    r.y = __float_as_uint(rw);
    // rec[wg][t][b-in-wg], wg = bg/NBR
    ((uint2*)(ws + REC_OFF))[((size_t)(bg >> 2) * Tt + t) * NBR + (bg & 3)] = r;
  } else if (id < T1 + T2 + T3) {
    int id3 = id - T1 - T2;
    int l = id3 & 63, kst = (id3 >> 6) & 7, w = (id3 >> 9) & 15, c = id3 >> 13;
    int lm = l & 15, lq = l >> 4;
    int row = 512 + 256 * c + 16 * w + lm;  // class g rows [512,768), o rows [768,1024)
    int k0  = kst * 32 + lq * 8;
    const float* src = Whh + (size_t)row * Hh + k0;
    unsigned short* dst = (unsigned short*)(ws + OBF_OFF) + (size_t)id3 * 8;
    #pragma unroll
    for (int jj = 0; jj < 8; ++jj) dst[jj] = bf16u(src[jj]);
  }
}

// ---------------- recurrent kernel: 32 WGs x 512 thr ----------------
__global__ __launch_bounds__(512, 2) void lstm_rec(
    const float* __restrict__ hidden, const float* __restrict__ Whh,
    const float* __restrict__ Wih,
    const unsigned char* __restrict__ ws, float* __restrict__ out)
{
  __shared__ alignas(16) short hbuf[4 * LDP2];           // 2.2 KB (4 real rows)
  __shared__ alignas(16) short ofrag[16 * 8 * 64 * 8];   // class o, all kst: 128 KB
  __shared__ alignas(16) float gbuf[NBR * Hh * 4];       // [m][j][p] fp32: 16 KB

  const unsigned short* obf = (const unsigned short*)(ws + OBF_OFF);
  const unsigned short* wxa = (const unsigned short*)(ws + WXA_OFF);
  const uint2* rec = (const uint2*)(ws + REC_OFF) + (size_t)blockIdx.x * Tt * NBR;

  const int tid = threadIdx.x;
  const int w   = tid >> 6;         // 0..7
  const int l   = tid & 63;
  const int lm  = l & 15;
  const int lq  = l >> 4;
  const int b0  = blockIdx.x * NBR;
  const int jb0 = 2 * w;            // wave owns col-blocks jb0, jb0+1

  // ---- register-resident weights: i,f all kst; g kst 0..1 ----
  short8 bif[2][2][8];   // [class][jb][kst]
  #pragma unroll
  for (int p = 0; p < 2; ++p)
    #pragma unroll
    for (int jb = 0; jb < 2; ++jb) {
      const float* row = Whh + (size_t)(256 * p + 16 * (jb0 + jb) + lm) * Hh;
      #pragma unroll
      for (int kst = 0; kst < 8; ++kst) {
        const int k0 = kst * 32 + lq * 8;
        short8 v;
        #pragma unroll
        for (int jj = 0; jj < 8; ++jj) v[jj] = (short)bf16u(row[k0 + jj]);
        bif[p][jb][kst] = v;
      }
    }
  short8 bg[2][2];       // class g, kst 0..1
  #pragma unroll
  for (int jb = 0; jb < 2; ++jb) {
    const float* row = Whh + (size_t)(512 + 16 * (jb0 + jb) + lm) * Hh;
    #pragma unroll
    for (int kst = 0; kst < 2; ++kst) {
      const int k0 = kst * 32 + lq * 8;
      short8 v;
      #pragma unroll
      for (int jj = 0; jj < 8; ++jj) v[jj] = (short)bf16u(row[k0 + jj]);
      bg[jb][kst] = v;
    }
  }
  // ---- class o fully into LDS (each wave writes its 2 col-blocks) ----
  #pragma unroll
  for (int jb = 0; jb < 2; ++jb) {
    const float* row = Whh + (size_t)(768 + 16 * (jb0 + jb) + lm) * Hh;
    #pragma unroll
    for (int kst = 0; kst < 8; ++kst) {
      const int k0 = kst * 32 + lq * 8;
      short8 v;
      #pragma unroll
      for (int jj = 0; jj < 8; ++jj) v[jj] = (short)bf16u(row[k0 + jj]);
      *(short8*)&ofrag[(((jb0 + jb) * 8 + kst) * 64 + l) * 8] = v;
    }
  }

  // ---- epilogue ownership: thread owns rows m0, m0+1 at h-col jE ----
  const int m0 = (tid >> 8) * 2;    // 0 or 2
  const int jE = tid & 255;
  float w80p[4], w81p[4];
  #pragma unroll
  for (int p = 0; p < 4; ++p) {
    const int g = p * 256 + jE;
    w80p[p] = Wih[(size_t)g * INED + 80];
    w81p[p] = Wih[(size_t)g * INED + 81];
  }
  float cst[2], hlast[2];
  #pragma unroll
  for (int r2 = 0; r2 < 2; ++r2) {
    cst[r2]   = hidden[(size_t)(b0 + m0 + r2) * (2 * Hh) + Hh + jE];
    hlast[r2] = 0.f;
  }

  // stage h(-1) into hbuf rows 0..3
  for (int v = tid; v < NBR * Hh; v += 512) {
    const int mm = v >> 8, k = v & 255;
    hbuf[mm * LDP2 + k] = (short)bf16u(hidden[(size_t)(b0 + mm) * (2 * Hh) + k]);
  }

  uint2 rc[2];
  rc[0] = rec[m0]; rc[1] = rec[m0 + 1];
  __syncthreads();

  for (int t = 0; t < Tt; ++t) {
    // early global issues: WXA gathers (epilogue use) + next-step records
    us4 gxa[2];
    #pragma unroll
    for (int r2 = 0; r2 < 2; ++r2) {
      const unsigned cc = rc[r2].x & 0xFFFFu;
      gxa[r2] = *(const us4*)(wxa + ((size_t)cc << 10) + ((unsigned)jE << 2));
    }
    const int tn = (t + 1 < Tt) ? (t + 1) : t;
    uint2 rcN[2];
    rcN[0] = rec[(size_t)tn * NBR + m0];
    rcN[1] = rec[(size_t)tn * NBR + m0 + 1];

    float4v acc[4][2];
    #pragma unroll
    for (int p = 0; p < 4; ++p)
      #pragma unroll
      for (int jb = 0; jb < 2; ++jb) acc[p][jb] = float4v{0.f, 0.f, 0.f, 0.f};

    #pragma unroll
    for (int kst = 0; kst < 8; ++kst) {
      short8 af = short8{0, 0, 0, 0, 0, 0, 0, 0};
      if (lm < 4) af = *(const short8*)(hbuf + lm * LDP2 + kst * 32 + lq * 8);
      #pragma unroll
      for (int jb = 0; jb < 2; ++jb) {
        const int jbG = jb0 + jb;
        acc[0][jb] = __builtin_amdgcn_mfma_f32_16x16x32_bf16(af, bif[0][jb][kst], acc[0][jb], 0, 0, 0);
        acc[1][jb] = __builtin_amdgcn_mfma_f32_16x16x32_bf16(af, bif[1][jb][kst], acc[1][jb], 0, 0, 0);
        short8 gf;
        if (kst < 2) gf = bg[jb][kst];
        else         gf = *(const short8*)(obf + (size_t)((jbG * 8 + kst) * 64 + l) * 8);
        acc[2][jb] = __builtin_amdgcn_mfma_f32_16x16x32_bf16(af, gf, acc[2][jb], 0, 0, 0);
        const short8 of = *(const short8*)&ofrag[((jbG * 8 + kst) * 64 + l) * 8];
        acc[3][jb] = __builtin_amdgcn_mfma_f32_16x16x32_bf16(af, of, acc[3][jb], 0, 0, 0);
      }
    }

    // redistribute valid rows (m = r, lanes lq==0) to gbuf[m][j][p]
    if (lq == 0) {
      #pragma unroll
      for (int jb = 0; jb < 2; ++jb) {
        const int j = 16 * (jb0 + jb) + lm;
        #pragma unroll
        for (int r = 0; r < 4; ++r) {
          float4v v4;
          v4[0] = acc[0][jb][r]; v4[1] = acc[1][jb][r];
          v4[2] = acc[2][jb][r]; v4[3] = acc[3][jb][r];
          *(float4v*)&gbuf[((r << 8) + j) << 2] = v4;
        }
      }
    }
    __syncthreads();   // bar1

    // dense epilogue: 2 h-values per thread
    #pragma unroll
    for (int r2 = 0; r2 < 2; ++r2) {
      const int m = m0 + r2;
      const float4v g4 = *(const float4v*)&gbuf[((m << 8) + jE) << 2];
      const float rw  = __uint_as_float(rc[r2].y);
      const float dnw = (rc[r2].x >> 16) ? 1.0f : 0.0f;
      const float iv = g4[0] + u2f(gxa[r2][0]) + rw * w80p[0] + dnw * w81p[0];
      const float fv = g4[1] + u2f(gxa[r2][1]) + rw * w80p[1] + dnw * w81p[1];
      const float gv = g4[2] + u2f(gxa[r2][2]) + rw * w80p[2] + dnw * w81p[2];
      const float ov = g4[3] + u2f(gxa[r2][3]) + rw * w80p[3] + dnw * w81p[3];
      const float c  = sigf(fv) * cst[r2] + sigf(iv) * tanhf_fast(gv);
      cst[r2] = c;
      const float hn = sigf(ov) * tanhf_fast(c);
      hlast[r2] = hn;
      out[((size_t)(b0 + m) * Tt + t) * Hh + jE] = hn;
      hbuf[m * LDP2 + jE] = (short)bf16u(hn);
    }
    rc[0] = rcN[0]; rc[1] = rcN[1];
    // bar2: LDS-only drain; out[] stores stay in flight (nothing reads them)
    asm volatile("s_waitcnt lgkmcnt(0)\n\ts_barrier" ::: "memory");
  }

  // final_hidden = [hT | cT], 2 rows per thread
  const size_t fbase = (size_t)Bb * Tt * Hh;
  #pragma unroll
  for (int r2 = 0; r2 < 2; ++r2) {
    const int m = m0 + r2;
    out[fbase + (size_t)(b0 + m) * (2 * Hh) + jE]      = hlast[r2];
    out[fbase + (size_t)(b0 + m) * (2 * Hh) + Hh + jE] = cst[r2];
  }
}

// ---------------- fallback (R1 kernel, known-correct, slow) ----------------
__global__ __launch_bounds__(1024, 4) void lstm_fused(
    const int* __restrict__ xs, const float* __restrict__ hidden,
    const int* __restrict__ pa, const float* __restrict__ prw,
    const float* __restrict__ pdn, const float* __restrict__ Wih,
    const float* __restrict__ Whh, const float* __restrict__ bih,
    const float* __restrict__ bhh, float* __restrict__ out)
{
  __shared__ alignas(16) short hbuf[2][NBat * LDP];
  const int tid = threadIdx.x;
  const int w = tid >> 6, l = tid & 63, lm = l & 15, lq = l >> 4;
  const int b0 = blockIdx.x * NBat;
  short8 bhhf[4][8];
  #pragma unroll
  for (int p = 0; p < 4; ++p) {
    const float* row = Whh + (size_t)(256 * p + 16 * w + lm) * Hh;
    #pragma unroll
    for (int kst = 0; kst < 8; ++kst) {
      short8 v;
      #pragma unroll
      for (int jj = 0; jj < 8; ++jj) v[jj] = (short)bf16u(row[kst * 32 + lq * 8 + jj]);
      bhhf[p][kst] = v;
    }
  }
  short8 bihf[4][3];
  #pragma unroll
  for (int p = 0; p < 4; ++p) {
    const float* row = Wih + (size_t)(256 * p + 16 * w + lm) * INED;
    #pragma unroll
    for (int ks = 0; ks < 3; ++ks) {
      short8 v;
      #pragma unroll
      for (int jj = 0; jj < 8; ++jj) {
        const int k = ks * 32 + lq * 8 + jj;
        v[jj] = (k < INED) ? (short)bf16u(row[k]) : (short)0;
      }
      bihf[p][ks] = v;
    }
  }
  const int j = 16 * w + lm;
  float bs[4];
  #pragma unroll
  for (int p = 0; p < 4; ++p) bs[p] = bih[256 * p + j] + bhh[256 * p + j];
  float cst[4], hlast[4];
  #pragma unroll
  for (int r = 0; r < 4; ++r) {
    cst[r] = hidden[(size_t)(b0 + lq * 4 + r) * (2 * Hh) + Hh + j];
    hlast[r] = 0.f;
  }
  for (int v = tid; v < NBat * Hh; v += 1024) {
    const int m = v >> 8, k = v & (Hh - 1);
    hbuf[1][m * LDP + k] = (short)bf16u(hidden[(size_t)(b0 + m) * (2 * Hh) + k]);
  }
  __syncthreads();
  const int xrow = (b0 + lm) * Tt;
  for (int t = 0; t < Tt; ++t) {
    const int xv = xs[xrow + t], av = pa[xrow + t];
    const unsigned short rwb = bf16u(prw[xrow + t]), dnb = bf16u(pdn[xrow + t]);
    const short* hb = hbuf[(t + 1) & 1];
    float4v acc[4];
    #pragma unroll
    for (int p = 0; p < 4; ++p) acc[p] = float4v{0.f, 0.f, 0.f, 0.f};
    #pragma unroll
    for (int kst = 0; kst < 8; ++kst) {
      const short8 af = *(const short8*)(hb + lm * LDP + kst * 32 + lq * 8);
      #pragma unroll
      for (int p = 0; p < 4; ++p)
        acc[p] = __builtin_amdgcn_mfma_f32_16x16x32_bf16(af, bhhf[p][kst], acc[p], 0, 0, 0);
    }
    #pragma unroll
    for (int ks = 0; ks < 3; ++ks) {
      short8 af;
      #pragma unroll
      for (int jj = 0; jj < 8; ++jj) {
        const int kk = ks * 32 + lq * 8 + jj;
        short v = ((kk == xv) || (kk == 64 + av)) ? (short)0x3F80 : (short)0;
        if (kk == 80) v = (short)rwb;
        if (kk == 81) v = (short)dnb;
        af[jj] = v;
      }
      #pragma unroll
      for (int p = 0; p < 4; ++p)
        acc[p] = __builtin_amdgcn_mfma_f32_16x16x32_bf16(af, bihf[p][ks], acc[p], 0, 0, 0);
    }
    short* hw = hbuf[t & 1];
    #pragma unroll
    for (int r = 0; r < 4; ++r) {
      const float iv = acc[0][r] + bs[0], fv = acc[1][r] + bs[1];
      const float gv = acc[2][r] + bs[2], ov = acc[3][r] + bs[3];
      const float c = sigf(fv) * cst[r] + sigf(iv) * tanhf_fast(gv);
      cst[r] = c;
      const float hn = sigf(ov) * tanhf_fast(c);
      hlast[r] = hn;
      const int m = lq * 4 + r;
      out[((size_t)(b0 + m) * Tt + t) * Hh + j] = hn;
      hw[m * LDP + j] = (short)bf16u(hn);
    }
    __syncthreads();
  }
  const size_t base = (size_t)Bb * Tt * Hh;
  #pragma unroll
  for (int r = 0; r < 4; ++r) {
    const int m = lq * 4 + r;
    out[base + (size_t)(b0 + m) * (2 * Hh) + j]      = hlast[r];
    out[base + (size_t)(b0 + m) * (2 * Hh) + Hh + j] = cst[r];
  }
}

}  // namespace

extern "C" void kernel_launch(void* const* d_in, const int* in_sizes, int n_in,
                              void* d_out, int out_size, void* d_ws, size_t ws_size,
                              hipStream_t stream) {
  const int*   xs     = (const int*)  d_in[0];
  const float* hidden = (const float*)d_in[1];
  const int*   pa     = (const int*)  d_in[2];
  const float* prw    = (const float*)d_in[3];
  const float* pdn    = (const float*)d_in[4];
  const float* Wih    = (const float*)d_in[5];
  const float* Whh    = (const float*)d_in[6];
  const float* bih    = (const float*)d_in[7];
  const float* bhh    = (const float*)d_in[8];
  float* out = (float*)d_out;

  if (ws_size >= WS_NEED) {
    unsigned char* ws = (unsigned char*)d_ws;
    const int prepN = (1024 * 1024 + Bb * Tt + 2 * 16 * 8 * 64 + 255) / 256;
    prep_kernel<<<dim3(prepN), dim3(256), 0, stream>>>(xs, pa, prw, pdn, Wih, Whh, bih, bhh, ws);
    lstm_rec<<<dim3(32), dim3(512), 0, stream>>>(hidden, Whh, Wih, ws, out);
  } else {
    lstm_fused<<<dim3(8), dim3(1024), 0, stream>>>(
        xs, hidden, pa, prw, pdn, Wih, Whh, bih, bhh, out);
  }
}

// Round 4
// 4224.044 us; speedup vs baseline: 2.4057x; 2.4057x over previous
//
#include <hip/hip_runtime.h>
#include <hip/hip_bf16.h>

// LSTM B=128,T=2048,H=256. R4: weight-PARTITIONED grid (no per-CU replication).
//  32 WGs x 512 thr: WG (rt,q) owns 16 batch rows (rt) x 64 h-cols (q).
//  Its Whh slice = 256 gate rows x 256 = 128 KB bf16 -> fully register-resident
//  (64 VGPR/thread). MFMA/CU drops 4x vs R2 (128 ops, all 16 A-rows valid);
//  the LDS/L2 weight streams are gone entirely.
//  Per step, h quarters are exchanged between the 4 column-WGs of a row-tile
//  via self-tagged 8B agent-scope atomics {tag=t+1 | 2xbf16}: tag travels with
//  data (no fences/flags/extra barriers). Parity double-buffer => overwrite-safe
//  (max skew 1 step). xg zeroed by prep each launch (stale-tag safety).
//  prep: WXA combo table bf16(Wih[:,x]+Wih[:,64+a]+bih+bhh) (2 MB, L3-hot),
//  packed records [rt][t][16], xg zero.

namespace {

constexpr int Tt   = 2048;
constexpr int Bb   = 128;
constexpr int Hh   = 256;
constexpr int NBat = 16;   // fallback rows/WG
constexpr int LDP  = 264;  // fallback hbuf pitch
constexpr int LDP3 = 272;  // rec hbuf pitch (shorts; bank-conflict-free af reads, r3-proven)
constexpr int GP   = 260;  // gbuf pitch (floats; 2-way banks on write/read)
constexpr int INED = 82;

constexpr size_t REC_OFF   = 0;
constexpr size_t REC_BYTES = (size_t)Bb * Tt * 8;        // 2 MB  [rt][t][16] uint2
constexpr size_t WXA_OFF   = REC_OFF + REC_BYTES;
constexpr size_t WXA_BYTES = (size_t)1024 * 1024 * 2;    // 2 MB  [c][j][p]
constexpr size_t XG_OFF    = WXA_OFF + WXA_BYTES;
constexpr size_t XG_BYTES  = (size_t)2 * 32 * 8 * 64 * 8;  // 256 KB ull-tagged h
constexpr size_t WS_NEED   = XG_OFF + XG_BYTES;

typedef __attribute__((ext_vector_type(8))) short short8;
typedef __attribute__((ext_vector_type(4))) float float4v;
typedef __attribute__((ext_vector_type(4))) unsigned short us4;

__device__ inline unsigned short bf16u(float f) {
  unsigned u = __float_as_uint(f);
  unsigned r = (u + 0x7FFFu + ((u >> 16) & 1u)) >> 16;  // RNE
  return (unsigned short)r;
}
__device__ inline float u2f(unsigned short u) {
  return __uint_as_float(((unsigned)u) << 16);
}
__device__ inline float sigf(float x) {
  float e = __builtin_amdgcn_exp2f(-1.4426950408889634f * x);
  return __builtin_amdgcn_rcpf(1.0f + e);
}
__device__ inline float tanhf_fast(float x) {
  float ax = __builtin_fabsf(x);
  float e  = __builtin_amdgcn_exp2f(-2.8853900817779268f * ax);
  float r  = (1.0f - e) * __builtin_amdgcn_rcpf(1.0f + e);
  return __builtin_copysignf(r, x);
}
__device__ inline size_t xgi(int par, int rt, int qq, int m0, int jj) {
  return ((size_t)((par * 32 + rt * 4 + qq) * 8 + m0)) * 64 + jj;
}

// ---------------- prep: WXA table (+bias), packed records, xg zero ----------------
__global__ __launch_bounds__(256) void prep_kernel(
    const int* __restrict__ xs, const int* __restrict__ pa,
    const float* __restrict__ prw, const float* __restrict__ pdn,
    const float* __restrict__ Wih, const float* __restrict__ bih,
    const float* __restrict__ bhh, unsigned char* __restrict__ ws)
{
  const int T1 = 1024 * 1024;   // WXA elements
  const int T2 = Bb * Tt;       // records
  const int T3 = 65536;         // xg zero (uints)
  int id = blockIdx.x * 256 + threadIdx.x;
  if (id < T1) {
    // WXA[c][j][p] = bf16(Wih[g][x] + Wih[g][64+a] + bih[g] + bhh[g]), g=p*256+j
    int c = id >> 10, qf = id & 1023, jj = qf >> 2, p = qf & 3;
    int x = c >> 4, a = c & 15;
    int g = p * 256 + jj;
    const float* row = Wih + (size_t)g * INED;
    ((unsigned short*)(ws + WXA_OFF))[id] = bf16u(row[x] + row[64 + a] + bih[g] + bhh[g]);
  } else if (id < T1 + T2) {
    int id2 = id - T1;
    int t = id2 & (Tt - 1), bg = id2 >> 11;
    const size_t src = (size_t)bg * Tt + t;
    int xv = xs[src], av = pa[src];
    float rw = prw[src];
    unsigned dnb = (pdn[src] != 0.0f) ? 1u : 0u;
    uint2 r;
    r.x = (unsigned)(xv * 16 + av) | (dnb << 16);
    r.y = __float_as_uint(rw);
    // rec[rt][t][m], rt = bg>>4, m = bg&15
    ((uint2*)(ws + REC_OFF))[((size_t)(bg >> 4) * Tt + t) * 16 + (bg & 15)] = r;
  } else if (id < T1 + T2 + T3) {
    ((unsigned*)(ws + XG_OFF))[id - T1 - T2] = 0u;   // stale-tag safety
  }
}

// ---------------- recurrent kernel: 32 WGs (rt,q), 512 thr ----------------
__global__ __launch_bounds__(512, 2) void lstm_rec(
    const float* __restrict__ hidden, const float* __restrict__ Whh,
    const float* __restrict__ Wih,
    unsigned char* __restrict__ ws, float* __restrict__ out)
{
  __shared__ alignas(16) short hbuf[16 * LDP3];   // 8.5 KB: full h(t-1), 16 rows x 256
  __shared__ alignas(16) float gbuf[16 * GP];     // 16.3 KB: MFMA results [m][gi]

  const unsigned short* wxa = (const unsigned short*)(ws + WXA_OFF);
  unsigned long long* xg = (unsigned long long*)(ws + XG_OFF);

  const int tid = threadIdx.x;
  const int w   = tid >> 6;         // wave 0..7
  const int l   = tid & 63;
  const int lm  = l & 15;
  const int lq  = l >> 4;
  const int wg  = blockIdx.x;
  const int rt  = wg & 7;           // row-tile (16 batch rows)
  const int q   = wg >> 3;          // column quarter (64 h-cols)
  const int b0  = rt * 16;
  const int jq0 = q * 64;

  // ---- register-resident weight slice: wave w -> gates gi in [32w, 32w+32) ----
  // gi = p*64 + jj  (p = gate class, jj = col within quarter)
  short8 bw[2][8];
  #pragma unroll
  for (int c = 0; c < 2; ++c) {
    const int gi = (2 * w + c) * 16 + lm;
    const int p  = gi >> 6, jj = gi & 63;
    const float* row = Whh + (size_t)(p * 256 + jq0 + jj) * Hh;
    #pragma unroll
    for (int kst = 0; kst < 8; ++kst) {
      const int k0 = kst * 32 + lq * 8;
      short8 v;
      #pragma unroll
      for (int e = 0; e < 8; ++e) v[e] = (short)bf16u(row[k0 + e]);
      bw[c][kst] = v;
    }
  }

  // ---- epilogue ownership: thread owns rows {m0, m0+8} at quarter-col jj ----
  const int m0 = tid >> 6;          // 0..7
  const int jj = tid & 63;
  const int jG = jq0 + jj;
  float w80p[4], w81p[4];
  #pragma unroll
  for (int p = 0; p < 4; ++p) {
    const int g = p * 256 + jG;
    w80p[p] = Wih[(size_t)g * INED + 80];
    w81p[p] = Wih[(size_t)g * INED + 81];
  }
  float cst[2], hlast[2];
  #pragma unroll
  for (int r2 = 0; r2 < 2; ++r2) {
    cst[r2]   = hidden[(size_t)(b0 + m0 + 8 * r2) * (2 * Hh) + Hh + jG];
    hlast[r2] = 0.f;
  }

  // stage full h(-1)
  for (int v = tid; v < 16 * 256; v += 512) {
    const int mm = v >> 8, k = v & 255;
    hbuf[mm * LDP3 + k] = (short)bf16u(hidden[(size_t)(b0 + mm) * (2 * Hh) + k]);
  }

  const uint2* recB = (const uint2*)(ws + REC_OFF) + (size_t)rt * Tt * 16;
  uint2 rc[2] = { recB[m0], recB[m0 + 8] };
  const int q1 = (q + 1) & 3, q2 = (q + 2) & 3, q3 = (q + 3) & 3;
  __syncthreads();

  for (int t = 0; t < Tt; ++t) {
    const int par = t & 1;
    // early global issues (consumed in epilogue; latency hides under MFMA+bar)
    us4 gxa[2];
    #pragma unroll
    for (int r2 = 0; r2 < 2; ++r2) {
      const unsigned cc = rc[r2].x & 0xFFFFu;
      gxa[r2] = *(const us4*)(wxa + ((size_t)cc << 10) + ((unsigned)jG << 2));
    }
    const int tn = (t + 1 < Tt) ? (t + 1) : t;
    uint2 rcN[2] = { recB[(size_t)tn * 16 + m0], recB[(size_t)tn * 16 + m0 + 8] };

    // ---- MFMA phase: 16 MFMAs/wave, all rows valid, B in regs ----
    float4v acc[2] = { float4v{0.f,0.f,0.f,0.f}, float4v{0.f,0.f,0.f,0.f} };
    #pragma unroll
    for (int kst = 0; kst < 8; ++kst) {
      const short8 af = *(const short8*)(hbuf + lm * LDP3 + kst * 32 + lq * 8);
      acc[0] = __builtin_amdgcn_mfma_f32_16x16x32_bf16(af, bw[0][kst], acc[0], 0, 0, 0);
      acc[1] = __builtin_amdgcn_mfma_f32_16x16x32_bf16(af, bw[1][kst], acc[1], 0, 0, 0);
    }
    #pragma unroll
    for (int c = 0; c < 2; ++c) {
      const int gi = (2 * w + c) * 16 + lm;
      #pragma unroll
      for (int r = 0; r < 4; ++r)
        gbuf[(lq * 4 + r) * GP + gi] = acc[c][r];
    }
    asm volatile("s_waitcnt lgkmcnt(0)\n\ts_barrier" ::: "memory");  // gbuf ready

    // ---- dense epilogue: 2 h-values/thread; publish FIRST ----
    unsigned short hb[2];
    #pragma unroll
    for (int r2 = 0; r2 < 2; ++r2) {
      const int m = m0 + 8 * r2;
      const float rw  = __uint_as_float(rc[r2].y);
      const float dnw = (rc[r2].x >> 16) ? 1.0f : 0.0f;
      const float iv = gbuf[m * GP +   0 + jj] + u2f(gxa[r2][0]) + rw * w80p[0] + dnw * w81p[0];
      const float fv = gbuf[m * GP +  64 + jj] + u2f(gxa[r2][1]) + rw * w80p[1] + dnw * w81p[1];
      const float gv = gbuf[m * GP + 128 + jj] + u2f(gxa[r2][2]) + rw * w80p[2] + dnw * w81p[2];
      const float ov = gbuf[m * GP + 192 + jj] + u2f(gxa[r2][3]) + rw * w80p[3] + dnw * w81p[3];
      const float c  = sigf(fv) * cst[r2] + sigf(iv) * tanhf_fast(gv);
      cst[r2] = c;
      const float hn = sigf(ov) * tanhf_fast(c);
      hlast[r2] = hn;
      hb[r2] = bf16u(hn);
    }
    // publish self-tagged word (tag rides with data -> no fence/flag needed)
    {
      const unsigned long long word =
          ((unsigned long long)(unsigned)(t + 1) << 32) |
          ((unsigned)hb[1] << 16) | (unsigned)hb[0];
      __hip_atomic_store(&xg[xgi(par, rt, q, m0, jj)], word,
                         __ATOMIC_RELAXED, __HIP_MEMORY_SCOPE_AGENT);
    }
    // own quarter into hbuf + out stores (off critical path for partners)
    #pragma unroll
    for (int r2 = 0; r2 < 2; ++r2) {
      const int m = m0 + 8 * r2;
      hbuf[m * LDP3 + jG] = (short)hb[r2];
      out[((size_t)(b0 + m) * Tt + t) * Hh + jG] = hlast[r2];
    }
    rc[0] = rcN[0]; rc[1] = rcN[1];

    if (t + 1 == Tt) break;

    // ---- exchange: spin on the 3 partner words this thread needs ----
    {
      const unsigned tag = (unsigned)(t + 1);
      unsigned long long* P1 = &xg[xgi(par, rt, q1, m0, jj)];
      unsigned long long* P2 = &xg[xgi(par, rt, q2, m0, jj)];
      unsigned long long* P3 = &xg[xgi(par, rt, q3, m0, jj)];
      // first round issued back-to-back (overlapped latency)
      unsigned long long v1 = __hip_atomic_load(P1, __ATOMIC_RELAXED, __HIP_MEMORY_SCOPE_AGENT);
      unsigned long long v2 = __hip_atomic_load(P2, __ATOMIC_RELAXED, __HIP_MEMORY_SCOPE_AGENT);
      unsigned long long v3 = __hip_atomic_load(P3, __ATOMIC_RELAXED, __HIP_MEMORY_SCOPE_AGENT);
      int guard = 0;
      while ((unsigned)(v1 >> 32) != tag && ++guard < (1 << 22))
        v1 = __hip_atomic_load(P1, __ATOMIC_RELAXED, __HIP_MEMORY_SCOPE_AGENT);
      while ((unsigned)(v2 >> 32) != tag && ++guard < (1 << 22))
        v2 = __hip_atomic_load(P2, __ATOMIC_RELAXED, __HIP_MEMORY_SCOPE_AGENT);
      while ((unsigned)(v3 >> 32) != tag && ++guard < (1 << 22))
        v3 = __hip_atomic_load(P3, __ATOMIC_RELAXED, __HIP_MEMORY_SCOPE_AGENT);
      hbuf[m0 * LDP3 + q1 * 64 + jj]       = (short)(v1 & 0xFFFFu);
      hbuf[(m0 + 8) * LDP3 + q1 * 64 + jj] = (short)((v1 >> 16) & 0xFFFFu);
      hbuf[m0 * LDP3 + q2 * 64 + jj]       = (short)(v2 & 0xFFFFu);
      hbuf[(m0 + 8) * LDP3 + q2 * 64 + jj] = (short)((v2 >> 16) & 0xFFFFu);
      hbuf[m0 * LDP3 + q3 * 64 + jj]       = (short)(v3 & 0xFFFFu);
      hbuf[(m0 + 8) * LDP3 + q3 * 64 + jj] = (short)((v3 >> 16) & 0xFFFFu);
    }
    asm volatile("s_waitcnt lgkmcnt(0)\n\ts_barrier" ::: "memory");  // hbuf ready
  }

  // final_hidden = [hT | cT]
  const size_t fbase = (size_t)Bb * Tt * Hh;
  #pragma unroll
  for (int r2 = 0; r2 < 2; ++r2) {
    const int m = m0 + 8 * r2;
    out[fbase + (size_t)(b0 + m) * (2 * Hh) + jG]      = hlast[r2];
    out[fbase + (size_t)(b0 + m) * (2 * Hh) + Hh + jG] = cst[r2];
  }
}

// ---------------- fallback (R1 kernel, known-correct, slow) ----------------
__global__ __launch_bounds__(1024, 4) void lstm_fused(
    const int* __restrict__ xs, const float* __restrict__ hidden,
    const int* __restrict__ pa, const float* __restrict__ prw,
    const float* __restrict__ pdn, const float* __restrict__ Wih,
    const float* __restrict__ Whh, const float* __restrict__ bih,
    const float* __restrict__ bhh, float* __restrict__ out)
{
  __shared__ alignas(16) short hbuf[2][NBat * LDP];
  const int tid = threadIdx.x;
  const int w = tid >> 6, l = tid & 63, lm = l & 15, lq = l >> 4;
  const int b0 = blockIdx.x * NBat;
  short8 bhhf[4][8];
  #pragma unroll
  for (int p = 0; p < 4; ++p) {
    const float* row = Whh + (size_t)(256 * p + 16 * w + lm) * Hh;
    #pragma unroll
    for (int kst = 0; kst < 8; ++kst) {
      short8 v;
      #pragma unroll
      for (int jj = 0; jj < 8; ++jj) v[jj] = (short)bf16u(row[kst * 32 + lq * 8 + jj]);
      bhhf[p][kst] = v;
    }
  }
  short8 bihf[4][3];
  #pragma unroll
  for (int p = 0; p < 4; ++p) {
    const float* row = Wih + (size_t)(256 * p + 16 * w + lm) * INED;
    #pragma unroll
    for (int ks = 0; ks < 3; ++ks) {
      short8 v;
      #pragma unroll
      for (int jj = 0; jj < 8; ++jj) {
        const int k = ks * 32 + lq * 8 + jj;
        v[jj] = (k < INED) ? (short)bf16u(row[k]) : (short)0;
      }
      bihf[p][ks] = v;
    }
  }
  const int j = 16 * w + lm;
  float bs[4];
  #pragma unroll
  for (int p = 0; p < 4; ++p) bs[p] = bih[256 * p + j] + bhh[256 * p + j];
  float cst[4], hlast[4];
  #pragma unroll
  for (int r = 0; r < 4; ++r) {
    cst[r] = hidden[(size_t)(b0 + lq * 4 + r) * (2 * Hh) + Hh + j];
    hlast[r] = 0.f;
  }
  for (int v = tid; v < NBat * Hh; v += 1024) {
    const int m = v >> 8, k = v & (Hh - 1);
    hbuf[1][m * LDP + k] = (short)bf16u(hidden[(size_t)(b0 + m) * (2 * Hh) + k]);
  }
  __syncthreads();
  const int xrow = (b0 + lm) * Tt;
  for (int t = 0; t < Tt; ++t) {
    const int xv = xs[xrow + t], av = pa[xrow + t];
    const unsigned short rwb = bf16u(prw[xrow + t]), dnb = bf16u(pdn[xrow + t]);
    const short* hb = hbuf[(t + 1) & 1];
    float4v acc[4];
    #pragma unroll
    for (int p = 0; p < 4; ++p) acc[p] = float4v{0.f, 0.f, 0.f, 0.f};
    #pragma unroll
    for (int kst = 0; kst < 8; ++kst) {
      const short8 af = *(const short8*)(hb + lm * LDP + kst * 32 + lq * 8);
      #pragma unroll
      for (int p = 0; p < 4; ++p)
        acc[p] = __builtin_amdgcn_mfma_f32_16x16x32_bf16(af, bhhf[p][kst], acc[p], 0, 0, 0);
    }
    #pragma unroll
    for (int ks = 0; ks < 3; ++ks) {
      short8 af;
      #pragma unroll
      for (int jj = 0; jj < 8; ++jj) {
        const int kk = ks * 32 + lq * 8 + jj;
        short v = ((kk == xv) || (kk == 64 + av)) ? (short)0x3F80 : (short)0;
        if (kk == 80) v = (short)rwb;
        if (kk == 81) v = (short)dnb;
        af[jj] = v;
      }
      #pragma unroll
      for (int p = 0; p < 4; ++p)
        acc[p] = __builtin_amdgcn_mfma_f32_16x16x32_bf16(af, bihf[p][ks], acc[p], 0, 0, 0);
    }
    short* hw = hbuf[t & 1];
    #pragma unroll
    for (int r = 0; r < 4; ++r) {
      const float iv = acc[0][r] + bs[0], fv = acc[1][r] + bs[1];
      const float gv = acc[2][r] + bs[2], ov = acc[3][r] + bs[3];
      const float c = sigf(fv) * cst[r] + sigf(iv) * tanhf_fast(gv);
      cst[r] = c;
      const float hn = sigf(ov) * tanhf_fast(c);
      hlast[r] = hn;
      const int m = lq * 4 + r;
      out[((size_t)(b0 + m) * Tt + t) * Hh + j] = hn;
      hw[m * LDP + j] = (short)bf16u(hn);
    }
    __syncthreads();
  }
  const size_t base = (size_t)Bb * Tt * Hh;
  #pragma unroll
  for (int r = 0; r < 4; ++r) {
    const int m = lq * 4 + r;
    out[base + (size_t)(b0 + m) * (2 * Hh) + j]      = hlast[r];
    out[base + (size_t)(b0 + m) * (2 * Hh) + Hh + j] = cst[r];
  }
}

}  // namespace

extern "C" void kernel_launch(void* const* d_in, const int* in_sizes, int n_in,
                              void* d_out, int out_size, void* d_ws, size_t ws_size,
                              hipStream_t stream) {
  const int*   xs     = (const int*)  d_in[0];
  const float* hidden = (const float*)d_in[1];
  const int*   pa     = (const int*)  d_in[2];
  const float* prw    = (const float*)d_in[3];
  const float* pdn    = (const float*)d_in[4];
  const float* Wih    = (const float*)d_in[5];
  const float* Whh    = (const float*)d_in[6];
  const float* bih    = (const float*)d_in[7];
  const float* bhh    = (const float*)d_in[8];
  float* out = (float*)d_out;

  if (ws_size >= WS_NEED) {
    unsigned char* ws = (unsigned char*)d_ws;
    const int prepN = (1024 * 1024 + Bb * Tt + 65536 + 255) / 256;
    prep_kernel<<<dim3(prepN), dim3(256), 0, stream>>>(xs, pa, prw, pdn, Wih, bih, bhh, ws);
    lstm_rec<<<dim3(32), dim3(512), 0, stream>>>(hidden, Whh, Wih, ws, out);
  } else {
    lstm_fused<<<dim3(8), dim3(1024), 0, stream>>>(
        xs, hidden, pa, prw, pdn, Wih, Whh, bih, bhh, out);
  }
}